// Round 8
// baseline (119.042 us; speedup 1.0000x reference)
//
#include <hip/hip_runtime.h>

// VectorQuantizer: split-precision bf16 MFMA (32x32x16), A=codebook / B=z swap:
// each lane owns one full row's argmin (3-reg select state), 2-wave blocks,
// single-buffered LDS chunks, cross-block TLP instead of intra-block pipelining.
// z [65536,192] f32, codebook [512,192] f32
// out: z_q [65536*192] f32 ++ indices [65536] (as float)

#define NROWS 65536
#define D     192
#define V     512
#define MARGIN 5e-4f
#define NCHUNK 16                 // V / 32 codes per chunk
#define CHUNK_BYTES 24576         // 32 codes * 192 k * 2B * 2 planes

typedef __attribute__((ext_vector_type(8)))  short short8;   // 8 bf16
typedef __attribute__((ext_vector_type(16))) float f32x16;   // 32x32 C frag

__device__ __forceinline__ unsigned short f2bf(float x) {    // RNE f32->bf16
    unsigned u = __float_as_uint(x);
    u += 0x7FFFu + ((u >> 16) & 1u);
    return (unsigned short)(u >> 16);
}
__device__ __forceinline__ float bf2f(unsigned short h) {
    return __uint_as_float(((unsigned)h) << 16);
}

// ---- prepass: codebook -> frag-linear bf16 hi/lo F + esq (unchanged, verified) ----
// unit u = ((c*12 + s)*2 + p)*64 + lane  (16B per unit)
//   code = c*32 + (lane&31), k = s*16 + (lane>>5)*8 + j
__global__ void vq_prep(const float* __restrict__ cb,
                        short8* __restrict__ F,
                        float* __restrict__ esq) {
    int u = blockIdx.x * 256 + threadIdx.x;        // 0..24575
    int lane = u & 63;
    int t = u >> 6;                                 // (c*12+s)*2+p
    int p = t & 1;
    int t2 = t >> 1;                                // c*12+s
    int c = t2 / 12, s = t2 - c * 12;
    int col  = c * 32 + (lane & 31);
    int koff = s * 16 + (lane >> 5) * 8;
    const float* src = cb + (size_t)col * D + koff;
    float4 a = *(const float4*)(src);
    float4 b = *(const float4*)(src + 4);
    float xs[8] = {a.x, a.y, a.z, a.w, b.x, b.y, b.z, b.w};
    short8 o;
    if (p == 0) {
#pragma unroll
        for (int j = 0; j < 8; ++j) o[j] = (short)f2bf(xs[j]);
    } else {
#pragma unroll
        for (int j = 0; j < 8; ++j) {
            unsigned short hb = f2bf(xs[j]);
            o[j] = (short)f2bf(xs[j] - bf2f(hb));
        }
    }
    F[u] = o;

    if (u < V) {                                    // esq, same order as rescan
        const float4* pp = (const float4*)(cb + (size_t)u * D);
        float4 es = make_float4(0.f, 0.f, 0.f, 0.f);
#pragma unroll
        for (int k = 0; k < D / 4; ++k) {
            float4 e = pp[k];
            es.x = fmaf(e.x, e.x, es.x); es.y = fmaf(e.y, e.y, es.y);
            es.z = fmaf(e.z, e.z, es.z); es.w = fmaf(e.w, e.w, es.w);
        }
        esq[u] = (es.x + es.y) + (es.z + es.w);
    }
}

// ---- exact fp32 rescan (round-1-verified bit-exact formula) ----
__device__ __noinline__ int vq_rescan(const float* __restrict__ z,
                                      const float* __restrict__ cb,
                                      const float* __restrict__ esq,
                                      int row, int lane) {
    const float4* zp = (const float4*)(z + (size_t)row * D);
    float4 s = make_float4(0.f, 0.f, 0.f, 0.f);
    for (int k = 0; k < D / 4; ++k) {
        float4 a = zp[k];
        s.x = fmaf(a.x, a.x, s.x); s.y = fmaf(a.y, a.y, s.y);
        s.z = fmaf(a.z, a.z, s.z); s.w = fmaf(a.w, a.w, s.w);
    }
    float zsq = (s.x + s.y) + (s.z + s.w);
    float bd = 3.402823466e+38f; int bi = V;
    for (int it = 0; it < V / 64; ++it) {
        int e = lane + it * 64;
        const float4* ep = (const float4*)(cb + (size_t)e * D);
        float4 a = make_float4(0.f, 0.f, 0.f, 0.f);
        for (int k = 0; k < D / 4; ++k) {
            float4 b = ep[k], zv = zp[k];
            a.x = fmaf(zv.x, b.x, a.x); a.y = fmaf(zv.y, b.y, a.y);
            a.z = fmaf(zv.z, b.z, a.z); a.w = fmaf(zv.w, b.w, a.w);
        }
        float dot = (a.x + a.y) + (a.z + a.w);
        float d = (zsq + esq[e]) - 2.f * dot;
        if (d < bd) { bd = d; bi = e; }
    }
    for (int m = 1; m < 64; m <<= 1) {
        float od = __shfl_xor(bd, m);
        int   oi = __shfl_xor(bi, m);
        if (od < bd || (od == bd && oi < bi)) { bd = od; bi = oi; }
    }
    return bi;
}

// ------------------------------ main kernel ------------------------------
__global__ __launch_bounds__(128, 3)
void vq_main(const float* __restrict__ z,
             const float* __restrict__ cb,
             const char* __restrict__ F,
             const float* __restrict__ esq,
             float* __restrict__ zq,
             float* __restrict__ idx_out) {
    __shared__ __align__(16) char lds_buf[CHUNK_BYTES];
    __shared__ float lds_esq[V];

    const int tid  = threadIdx.x;
    const int wave = tid >> 6;
    const int lane = tid & 63;
    const int l31  = lane & 31;
    const int half = lane >> 5;

    const int rowbase = blockIdx.x * 64 + wave * 32;
    const int myrow   = rowbase + l31;              // this lane's row

    // esq -> LDS (all 128 threads, 4 floats each)
    ((float4*)lds_esq)[tid] = ((const float4*)esq)[tid];

    // ---- B prologue: z row -> 12 k-step hi/lo frags (lane covers k-block `half`) ----
    short8 zhi[12], zlo[12];
    {
        const float* zr = z + (size_t)myrow * D + half * 8;
#pragma unroll
        for (int s = 0; s < 12; ++s) {
            float4 a = *(const float4*)(zr + s * 16);
            float4 b = *(const float4*)(zr + s * 16 + 4);
            float xs[8] = {a.x, a.y, a.z, a.w, b.x, b.y, b.z, b.w};
            short8 h, l;
#pragma unroll
            for (int j = 0; j < 8; ++j) {
                unsigned short hb = f2bf(xs[j]);
                h[j] = (short)hb;
                l[j] = (short)f2bf(xs[j] - bf2f(hb));
            }
            zhi[s] = h; zlo[s] = l;
        }
    }

    float v1 = 3.402823466e+38f, v2 = 3.402823466e+38f;
    int   i1 = 0;

    for (int c = 0; c < NCHUNK; ++c) {
        __syncthreads();                            // prior chunk reads done (+esq write)

        // ---- stage chunk c (24 KB, 12 x 16B per thread, linear) ----
        {
            const char* gsrc = F + (size_t)c * CHUNK_BYTES + tid * 16;
            char* ldst = &lds_buf[0] + tid * 16;
#pragma unroll
            for (int it = 0; it < 12; ++it)
                __builtin_amdgcn_global_load_lds(
                    (const __attribute__((address_space(1))) void*)(gsrc + it * 2048),
                    (__attribute__((address_space(3))) void*)(ldst + it * 2048),
                    16, 0, 0);
        }
        __syncthreads();                            // stage complete (compiler drains vmcnt)

        // ---- MFMA: A = codebook frags (LDS), B = z frags (regs) ----
        f32x16 acc1, acc23;
#pragma unroll
        for (int q = 0; q < 16; ++q) { acc1[q] = 0.f; acc23[q] = 0.f; }

#pragma unroll
        for (int s = 0; s < 12; ++s) {
            short8 eh = *(const short8*)(&lds_buf[0] + (s * 2 + 0) * 1024 + lane * 16);
            short8 el = *(const short8*)(&lds_buf[0] + (s * 2 + 1) * 1024 + lane * 16);
            acc1  = __builtin_amdgcn_mfma_f32_32x32x16_bf16(eh, zhi[s], acc1,  0, 0, 0);
            acc23 = __builtin_amdgcn_mfma_f32_32x32x16_bf16(el, zhi[s], acc23, 0, 0, 0);
            acc23 = __builtin_amdgcn_mfma_f32_32x32x16_bf16(eh, zlo[s], acc23, 0, 0, 0);
        }

        // ---- per-lane top-2 over this chunk's 16 codes (ascending order) ----
        // C layout (m74/m101): code = c0 + (q&3) + 8*(q>>2) + 4*half ; col = lane&31 = row
        const int c0 = c * 32;
#pragma unroll
        for (int G = 0; G < 4; ++G) {
            const int cbase = c0 + half * 4 + G * 8;
            float4 ev = *(const float4*)(lds_esq + cbase);
#pragma unroll
            for (int j = 0; j < 4; ++j) {
                const int q = G * 4 + j;
                float e = (j == 0) ? ev.x : (j == 1) ? ev.y : (j == 2) ? ev.z : ev.w;
                float d = fmaf(-2.f, acc1[q] + acc23[q], e);
                bool b = d < v1;
                v2 = fminf(fmaxf(d, v1), v2);       // loser of (d, v1_old) into v2
                i1 = b ? (cbase + j) : i1;
                v1 = b ? d : v1;
            }
        }
    }

    // ---- merge the two half-lanes (disjoint code subsets, same row) ----
    {
        float ov1 = __shfl_xor(v1, 32);
        int   oi1 = __shfl_xor(i1, 32);
        float ov2 = __shfl_xor(v2, 32);
        bool take = (ov1 < v1) || ((ov1 == v1) && (oi1 < i1));
        v2 = fminf(fminf(v2, ov2), take ? v1 : ov1);
        if (take) { v1 = ov1; i1 = oi1; }
    }

    // ---- rare exact rescan (per-row ballot, wave-uniform loop) ----
    {
        bool need = (v2 - v1) <= MARGIN;
        unsigned long long bm = __ballot(need) & 0xFFFFFFFFull;  // rows = lanes 0..31
        while (bm) {
            int r = __ffsll((long long)bm) - 1;
            bm &= bm - 1;
            int ridx = vq_rescan(z, cb, esq, rowbase + r, lane);
            if (l31 == r) i1 = ridx;                // both half-lanes of row r update
        }
    }

    // ---- write: pair (l31, l31+32) copies cb[i1] -> zq[row]; lane<32 writes idx ----
    {
        const int row = rowbase + l31;
        const float4* srcv = (const float4*)(cb + (size_t)i1 * D);
        float4* dstv = (float4*)(zq + (size_t)row * D);
#pragma unroll
        for (int j = 0; j < 24; ++j)
            dstv[half * 24 + j] = srcv[half * 24 + j];
        if (half == 0) idx_out[row] = (float)i1;
    }
}

// --------- round-1 fallback (only if ws is unexpectedly small) ---------
#define TV 32
#define FBLOCK 128
__global__ __launch_bounds__(FBLOCK, 2)
void vq_argmin_fallback(const float* __restrict__ z, const float* __restrict__ cb,
                        float* __restrict__ zq, float* __restrict__ idx_out) {
    __shared__ float lds_cb[TV * D];
    __shared__ float lds_esq2[TV];
    const int row = blockIdx.x * FBLOCK + threadIdx.x;
    float4 zr[D / 4];
    const float4* zp = (const float4*)(z + (size_t)row * D);
    float4 s = make_float4(0.f, 0.f, 0.f, 0.f);
#pragma unroll
    for (int i = 0; i < D / 4; ++i) {
        zr[i] = zp[i];
        s.x = fmaf(zr[i].x, zr[i].x, s.x); s.y = fmaf(zr[i].y, zr[i].y, s.y);
        s.z = fmaf(zr[i].z, zr[i].z, s.z); s.w = fmaf(zr[i].w, zr[i].w, s.w);
    }
    const float zsq = (s.x + s.y) + (s.z + s.w);
    float best = 3.4e38f; int bidx = 0;
    for (int vt = 0; vt < V / TV; ++vt) {
        __syncthreads();
        const float4* cbp = (const float4*)(cb + (size_t)vt * TV * D);
        float4* l4 = (float4*)lds_cb;
#pragma unroll
        for (int i = 0; i < (TV * D / 4) / FBLOCK; ++i)
            l4[threadIdx.x + i * FBLOCK] = cbp[threadIdx.x + i * FBLOCK];
        __syncthreads();
        if (threadIdx.x < TV) {
            const float* e = lds_cb + threadIdx.x * D;
            float4 es = make_float4(0.f, 0.f, 0.f, 0.f);
#pragma unroll
            for (int k = 0; k < D; k += 4) {
                es.x = fmaf(e[k], e[k], es.x); es.y = fmaf(e[k+1], e[k+1], es.y);
                es.z = fmaf(e[k+2], e[k+2], es.z); es.w = fmaf(e[k+3], e[k+3], es.w);
            }
            lds_esq2[threadIdx.x] = (es.x + es.y) + (es.z + es.w);
        }
        __syncthreads();
#pragma unroll 2
        for (int v = 0; v < TV; ++v) {
            const float4* e4 = (const float4*)(lds_cb + v * D);
            float4 a = make_float4(0.f, 0.f, 0.f, 0.f);
#pragma unroll
            for (int k = 0; k < D / 4; ++k) {
                float4 b = e4[k];
                a.x = fmaf(zr[k].x, b.x, a.x); a.y = fmaf(zr[k].y, b.y, a.y);
                a.z = fmaf(zr[k].z, b.z, a.z); a.w = fmaf(zr[k].w, b.w, a.w);
            }
            const float dot = (a.x + a.y) + (a.z + a.w);
            const float dist = (zsq + lds_esq2[v]) - 2.f * dot;
            if (dist < best) { best = dist; bidx = vt * TV + v; }
        }
    }
    float4* zqp = (float4*)(zq + (size_t)row * D);
    const float4* bp = (const float4*)(cb + (size_t)bidx * D);
#pragma unroll
    for (int i = 0; i < D / 4; ++i) zqp[i] = bp[i];
    idx_out[row] = (float)bidx;
}

extern "C" void kernel_launch(void* const* d_in, const int* in_sizes, int n_in,
                              void* d_out, int out_size, void* d_ws, size_t ws_size,
                              hipStream_t stream) {
    const float* z  = (const float*)d_in[0];
    const float* cb = (const float*)d_in[1];
    float* zq      = (float*)d_out;
    float* idx_out = (float*)d_out + (size_t)NROWS * D;

    const size_t f_bytes = (size_t)NCHUNK * CHUNK_BYTES;    // 393216
    const size_t need = f_bytes + V * sizeof(float);
    if (ws_size < need) {
        vq_argmin_fallback<<<NROWS / FBLOCK, FBLOCK, 0, stream>>>(z, cb, zq, idx_out);
        return;
    }
    short8* F  = (short8*)d_ws;
    float* esq = (float*)((char*)d_ws + f_bytes);

    vq_prep<<<96, 256, 0, stream>>>(cb, F, esq);
    vq_main<<<NROWS / 64, 128, 0, stream>>>(z, cb, (const char*)F, esq, zq, idx_out);
}